// Round 2
// baseline (5667.205 us; speedup 1.0000x reference)
//
#include <hip/hip_runtime.h>
#include <hip/hip_bf16.h>

#define SEQ 2048
#define NB  64
#define NIN 128
#define NH  256
// A-term layout: [t][group][gate][wave][ntile][lane][reg] bf16
#define AT_PER_TG 12288
#define HSTRIDE 296   // 148 dwords ≡ 20 (mod 32): spreads column-slice writes

typedef __bf16 bf16x8 __attribute__((ext_vector_type(8)));
typedef __bf16 bf16x4 __attribute__((ext_vector_type(4)));
typedef float  f32x4  __attribute__((ext_vector_type(4)));

#define MFMA16 __builtin_amdgcn_mfma_f32_16x16x32_bf16

__device__ __forceinline__ float fast_sigmoid(float x) {
    float e = __builtin_amdgcn_exp2f(-1.4426950408889634f * x);
    return __builtin_amdgcn_rcpf(1.0f + e);
}
__device__ __forceinline__ float fast_tanh(float x) {
    float e = __builtin_amdgcn_exp2f(2.8853900817779268f * x);
    return 1.0f - 2.0f * __builtin_amdgcn_rcpf(1.0f + e);
}

// ---------- phase 1: A-terms = x @ Wg_x^T  (frag-ordered bf16) -------------
__global__ __launch_bounds__(256) void gru_pre(
        const float* __restrict__ x, const float* __restrict__ Wz,
        const float* __restrict__ Wr, const float* __restrict__ Wi,
        __bf16* __restrict__ At) {
    __shared__ __align__(16) __bf16 wlds[256][136];
    __shared__ __align__(16) __bf16 xlds[64][136];
    const int bid = blockIdx.x;
    const int t = bid / 3, gate = bid - t * 3;
    const float* W = (gate == 0) ? Wz : ((gate == 1) ? Wr : Wi);
    const int xoff = (gate == 2) ? NH : 0;   // Wi is [h, x] (hidden-first)
    const int tid = threadIdx.x;
    #pragma unroll
    for (int j = 0; j < 32; ++j) {
        int flat = j * 1024 + tid * 4;
        int row = flat >> 7, col = flat & 127;
        const float4 v = *(const float4*)(W + (size_t)row * 384 + xoff + col);
        wlds[row][col+0] = (__bf16)v.x; wlds[row][col+1] = (__bf16)v.y;
        wlds[row][col+2] = (__bf16)v.z; wlds[row][col+3] = (__bf16)v.w;
    }
    const float* xt = x + (size_t)t * (NB * NIN);
    #pragma unroll
    for (int j = 0; j < 8; ++j) {
        int flat = j * 1024 + tid * 4;
        int row = flat >> 7, col = flat & 127;
        const float4 v = *(const float4*)(xt + row * NIN + col);
        xlds[row][col+0] = (__bf16)v.x; xlds[row][col+1] = (__bf16)v.y;
        xlds[row][col+2] = (__bf16)v.z; xlds[row][col+3] = (__bf16)v.w;
    }
    __syncthreads();
    const int wv = tid >> 6, l = tid & 63;
    const int lrow = l & 15, lk = (l >> 4) * 8;
    bf16x8 a[4];
    #pragma unroll
    for (int kt = 0; kt < 4; ++kt)
        a[kt] = *(const bf16x8*)&xlds[wv * 16 + lrow][kt * 32 + lk];
    #pragma unroll
    for (int j = 0; j < 16; ++j) {
        f32x4 acc = {0.f, 0.f, 0.f, 0.f};
        #pragma unroll
        for (int kt = 0; kt < 4; ++kt) {
            bf16x8 b = *(const bf16x8*)&wlds[j * 16 + lrow][kt * 32 + lk];
            acc = MFMA16(a[kt], b, acc, 0, 0, 0);
        }
        size_t off = (size_t)(t * 4 + wv) * AT_PER_TG
                   + (size_t)(((gate * 8 + (j >> 1)) * 2 + (j & 1)) * 256 + l * 4);
        bf16x4 o;
        o[0]=(__bf16)acc[0]; o[1]=(__bf16)acc[1]; o[2]=(__bf16)acc[2]; o[3]=(__bf16)acc[3];
        *(bf16x4*)(At + off) = o;
    }
}

// ---------- phase 2: recurrence ---------------------------------------------
#define DECLW(p) f32x4 W##p##0, W##p##1, W##p##2, W##p##3, W##p##4, W##p##5, W##p##6, W##p##7

#define LDW1(dst, base, kt) do { \
    const float4 v0_ = *(const float4*)((base) + (kt)*32 + lk); \
    const float4 v1_ = *(const float4*)((base) + (kt)*32 + lk + 4); \
    bf16x8 f_; \
    f_[0]=(__bf16)v0_.x; f_[1]=(__bf16)v0_.y; f_[2]=(__bf16)v0_.z; f_[3]=(__bf16)v0_.w; \
    f_[4]=(__bf16)v1_.x; f_[5]=(__bf16)v1_.y; f_[6]=(__bf16)v1_.z; f_[7]=(__bf16)v1_.w; \
    dst = __builtin_bit_cast(f32x4, f_); } while (0)

#define LDW8(p, base) do { LDW1(W##p##0,base,0); LDW1(W##p##1,base,1); \
    LDW1(W##p##2,base,2); LDW1(W##p##3,base,3); LDW1(W##p##4,base,4); \
    LDW1(W##p##5,base,5); LDW1(W##p##6,base,6); LDW1(W##p##7,base,7); } while (0)

#define PIN8(p) asm volatile("" : "+a"(W##p##0), "+a"(W##p##1), "+a"(W##p##2), \
    "+a"(W##p##3), "+a"(W##p##4), "+a"(W##p##5), "+a"(W##p##6), "+a"(W##p##7))

#define BW(p,k) __builtin_bit_cast(bf16x8, W##p##k)

#define GLOAD(srcp, dstp) __builtin_amdgcn_global_load_lds( \
    (const __attribute__((address_space(1))) void*)(srcp), \
    (__attribute__((address_space(3))) void*)(dstp), 16, 0, 0)

#define ACCINIT(dst, chunk, nt) do { \
    bf16x4 tv_ = *(const bf16x4*)(rb + ((chunk)*2+(nt))*256 + l*4); \
    dst[0]=(float)tv_[0]; dst[1]=(float)tv_[1]; dst[2]=(float)tv_[2]; dst[3]=(float)tv_[3]; } while (0)

// phase A: z+r GEMMs share the hBuf read
#define ASTEP(k) do { bf16x8 ha_ = *(const bf16x8*)(hr + (k)*32); \
    az0 = MFMA16(ha_, BW(00,k), az0, 0,0,0); az1 = MFMA16(ha_, BW(01,k), az1, 0,0,0); \
    ar0 = MFMA16(ha_, BW(10,k), ar0, 0,0,0); ar1 = MFMA16(ha_, BW(11,k), ar1, 0,0,0); } while (0)

// phase B: inter GEMM on r*h
#define ISTEP(k) do { bf16x8 ra_ = *(const bf16x8*)(rr + (k)*32); \
    ai0 = MFMA16(ra_, BW(20,k), ai0, 0,0,0); ai1 = MFMA16(ra_, BW(21,k), ai1, 0,0,0); } while (0)

__global__ __launch_bounds__(512, 2) void gru_rec(
        const float* __restrict__ h0, const float* __restrict__ Wz,
        const float* __restrict__ Wr, const float* __restrict__ Wi,
        const __bf16* __restrict__ At, float* __restrict__ out) {
    __shared__ __align__(16) __bf16 hB[16][HSTRIDE];
    __shared__ __align__(16) __bf16 rhB[16][HSTRIDE];
    __shared__ __align__(16) __bf16 ring[4][AT_PER_TG];
    const int g = blockIdx.x;
    const int tid = threadIdx.x;
    const int wv = tid >> 6, l = tid & 63;
    const int lrow = l & 15;       // A row / C col
    const int lk = (l >> 4) * 8;   // k-slice base
    const int crow = (l >> 4) * 4; // C row base
    const int hid0 = wv * 32 + lrow;

    // ---- recurrent weights: 48 named f32x4 frags pinned to AGPRs ----
    DECLW(00); DECLW(01); DECLW(10); DECLW(11); DECLW(20); DECLW(21);
    {
        const float* bz0 = Wz + (size_t)hid0 * 384 + 128;
        const float* bz1 = Wz + (size_t)(hid0 + 16) * 384 + 128;
        const float* br0 = Wr + (size_t)hid0 * 384 + 128;
        const float* br1 = Wr + (size_t)(hid0 + 16) * 384 + 128;
        const float* bi0 = Wi + (size_t)hid0 * 384;       // Wi hidden-first
        const float* bi1 = Wi + (size_t)(hid0 + 16) * 384;
        LDW8(00, bz0); LDW8(01, bz1);
        LDW8(10, br0); LDW8(11, br1);
        LDW8(20, bi0); LDW8(21, bi1);
    }
    PIN8(00); PIN8(01); PIN8(10); PIN8(11); PIN8(20); PIN8(21);

    // ---- init h (f32 regs, C-frag coords) + hB ----
    float h[2][4];
    #pragma unroll
    for (int nt = 0; nt < 2; ++nt)
        #pragma unroll
        for (int q = 0; q < 4; ++q) {
            float v = h0[(size_t)(g * 16 + crow + q) * NH + hid0 + nt * 16];
            h[nt][q] = v;
            hB[crow + q][hid0 + nt * 16] = (__bf16)v;
        }
    // ---- prologue: prefetch ring slots 0..2 (wave loads only its own chunks) ----
    #pragma unroll
    for (int s = 0; s < 3; ++s) {
        #pragma unroll
        for (int gg = 0; gg < 3; ++gg) {
            const int chunk = gg * 8 + wv;
            const __bf16* src = At + (size_t)(s * 4 + g) * AT_PER_TG + chunk * 512 + l * 8;
            GLOAD(src, &ring[s][chunk * 512]);
        }
    }
    asm volatile("s_waitcnt lgkmcnt(0)" ::: "memory");
    __builtin_amdgcn_s_barrier();

    // per-thread prefetch base for tp = 3 (chunk wv; +8*512 / +16*512 for the others)
    const __bf16* pf = At + (size_t)(3 * 4 + g) * AT_PER_TG + wv * 512 + l * 8;
    float* outp = out + (size_t)(g * 16 + crow) * NH + hid0;

    #pragma clang loop unroll(disable)
    for (int t = 0; t < SEQ; ++t) {
        const int slot = t & 3;
        const int sp = (t + 3) & 3;
        // issue prefetch for t+3 (tail: re-issues SEQ-1 into a dead slot)
        GLOAD(pf,            &ring[sp][(0 * 8 + wv) * 512]);
        GLOAD(pf + 8 * 512,  &ring[sp][(1 * 8 + wv) * 512]);
        GLOAD(pf + 16 * 512, &ring[sp][(2 * 8 + wv) * 512]);
        if (t < SEQ - 4) pf += 4 * AT_PER_TG;
        // robust: drain everything but the 3 just-issued loads (slot-t loads are
        // 3 steps old -> already complete; immune to compiler-injected VMEM ops)
        asm volatile("s_waitcnt vmcnt(3)" ::: "memory");

        const __bf16* rb = &ring[slot][0];
        const __bf16* hr = &hB[lrow][lk];
        // ---- phase A: z,r GEMMs (shared hB read), acc init from x-terms ----
        f32x4 az0, az1, ar0, ar1;
        ACCINIT(az0, 0 + wv, 0);  ACCINIT(az1, 0 + wv, 1);
        ACCINIT(ar0, 8 + wv, 0);  ACCINIT(ar1, 8 + wv, 1);
        ASTEP(0); ASTEP(1); ASTEP(2); ASTEP(3);
        ASTEP(4); ASTEP(5); ASTEP(6); ASTEP(7);
        // r sigmoid + r*h write first (critical path), z sigmoid overlaps barrier
        #pragma unroll
        for (int nt = 0; nt < 2; ++nt)
            #pragma unroll
            for (int q = 0; q < 4; ++q) {
                float r = fast_sigmoid(nt ? ar1[q] : ar0[q]);
                rhB[crow + q][hid0 + nt * 16] = (__bf16)(r * h[nt][q]);
            }
        float zv[2][4];
        #pragma unroll
        for (int nt = 0; nt < 2; ++nt)
            #pragma unroll
            for (int q = 0; q < 4; ++q)
                zv[nt][q] = fast_sigmoid(nt ? az1[q] : az0[q]);
        asm volatile("s_waitcnt lgkmcnt(0)" ::: "memory");
        __builtin_amdgcn_s_barrier();

        // ---- phase B: inter GEMM on (r*h) ----
        f32x4 ai0, ai1;
        ACCINIT(ai0, 16 + wv, 0);  ACCINIT(ai1, 16 + wv, 1);
        const __bf16* rr = &rhB[lrow][lk];
        ISTEP(0); ISTEP(1); ISTEP(2); ISTEP(3);
        ISTEP(4); ISTEP(5); ISTEP(6); ISTEP(7);
        // tanh, blend, store out + hB for next step
        #pragma unroll
        for (int nt = 0; nt < 2; ++nt)
            #pragma unroll
            for (int q = 0; q < 4; ++q) {
                float it = fast_tanh(nt ? ai1[q] : ai0[q]);
                float hn = h[nt][q] + zv[nt][q] * (it - h[nt][q]);
                h[nt][q] = hn;
                outp[(size_t)q * NH + nt * 16] = hn;
                hB[crow + q][hid0 + nt * 16] = (__bf16)hn;
            }
        outp += NB * NH;
        asm volatile("s_waitcnt lgkmcnt(0)" ::: "memory");
        __builtin_amdgcn_s_barrier();
    }
}

extern "C" void kernel_launch(void* const* d_in, const int* in_sizes, int n_in,
                              void* d_out, int out_size, void* d_ws, size_t ws_size,
                              hipStream_t stream) {
    const float* x  = (const float*)d_in[0];
    const float* h0 = (const float*)d_in[1];
    const float* Wz = (const float*)d_in[2];
    const float* Wr = (const float*)d_in[3];
    const float* Wi = (const float*)d_in[4];
    __bf16* At = (__bf16*)d_ws;   // SEQ*4*AT_PER_TG*2 = 192 MiB
    (void)in_sizes; (void)n_in; (void)out_size; (void)ws_size;

    gru_pre<<<dim3(SEQ * 3), dim3(256), 0, stream>>>(x, Wz, Wr, Wi, At);
    gru_rec<<<dim3(4), dim3(512), 0, stream>>>(h0, Wz, Wr, Wi, At, (float*)d_out);
}